// Round 1
// baseline (434.490 us; speedup 1.0000x reference)
//
#include <hip/hip_runtime.h>

// 1x1 conv as batched GEMM: out[b] (COUT x HW) = Wt (COUT x CIN) * x[b] (CIN x HW)
// bf16 MFMA (fp32 accumulate), memory-bound target ~85us.

#define HW   16384
#define CIN  128
#define COUT 128
#define NB   32

typedef __bf16 bf16x8 __attribute__((ext_vector_type(8)));
typedef float f32x16 __attribute__((ext_vector_type(16)));
typedef unsigned short ushort8 __attribute__((ext_vector_type(8)));

__device__ __forceinline__ unsigned short f32_to_bf16(float f) {
    unsigned int u = __float_as_uint(f);
    u += 0x7FFFu + ((u >> 16) & 1u);   // round-to-nearest-even
    return (unsigned short)(u >> 16);
}

// W (CIN x COUT fp32) -> Wt (COUT x CIN bf16), transposed+converted, in ws.
__global__ void conv_prep(const float* __restrict__ w, unsigned short* __restrict__ wt) {
    int t = blockIdx.x * 256 + threadIdx.x;   // 64 blocks * 256 = 16384
    int i = t >> 7;      // cin
    int o = t & 127;     // cout (contiguous across lanes -> coalesced read)
    wt[o * CIN + i] = f32_to_bf16(w[i * COUT + o]);
}

__global__ __launch_bounds__(256, 2) void conv_main(
        const float* __restrict__ x, const unsigned short* __restrict__ wt,
        float* __restrict__ out) {
    // xT[s][i] bf16, 128 rows x 16 chunks of 8 elems (16B), chunk XOR-swizzled by (s&15).
    __shared__ unsigned short lds[CIN * 128];   // 32 KB

    const int bx = blockIdx.x;
    const int b  = bx >> 7;             // batch
    const int s0 = (bx & 127) * 128;    // spatial tile start

    const int t    = threadIdx.x;
    const int lane = t & 63;
    const int wv   = t >> 6;            // wave 0..3

    // ---- stage x tile (CIN x 128) -> LDS as bf16 xT[s][i], swizzled ----
    {
        const int s_loc = t & 127;
        const float* xp = x + (size_t)b * CIN * HW + s0 + s_loc;
        #pragma unroll
        for (int iter = 0; iter < 8; ++iter) {
            int i0 = ((t >> 7) + 2 * iter) * 8;       // i-chunk base, covers all 16 chunks
            float v[8];
            #pragma unroll
            for (int j = 0; j < 8; ++j)
                v[j] = xp[(size_t)(i0 + j) * HW];     // coalesced 256B per wave-instr
            ushort8 p;
            #pragma unroll
            for (int j = 0; j < 8; ++j)
                p[j] = f32_to_bf16(v[j]);
            int chunk = (i0 >> 3) ^ (s_loc & 15);
            *(ushort8*)((char*)lds + s_loc * 256 + chunk * 16) = p;  // ds_write_b128
        }
    }

    // ---- A fragments straight from global Wt (32KB, L1-resident) ----
    // A[m=o][k = kstep*16 + half*8 + j], j=0..7 contiguous
    bf16x8 afrag[8];
    {
        int o    = wv * 32 + (lane & 31);
        int half = lane >> 5;
        const char* wp = (const char*)wt + (size_t)(o * CIN + half * 8) * 2;
        #pragma unroll
        for (int k = 0; k < 8; ++k)
            afrag[k] = *(const bf16x8*)(wp + k * 32);   // 16B aligned dwordx4
    }

    __syncthreads();

    // ---- K loop: each wave computes o in [32*wv, 32*wv+32), all 128 s ----
    f32x16 acc[4];
    #pragma unroll
    for (int c = 0; c < 4; ++c) acc[c] = (f32x16)(0.0f);

    const int srow = lane & 31;
    const int half = lane >> 5;
    #pragma unroll
    for (int k = 0; k < 8; ++k) {
        int cbase = k * 2 + half;                  // i-chunk index for this frag
        #pragma unroll
        for (int c = 0; c < 4; ++c) {
            int s = c * 32 + srow;
            int chunk = cbase ^ (s & 15);
            bf16x8 bfrag = *(const bf16x8*)((const char*)lds + s * 256 + chunk * 16);
            acc[c] = __builtin_amdgcn_mfma_f32_32x32x16_bf16(afrag[k], bfrag, acc[c], 0, 0, 0);
        }
    }

    // ---- epilogue: C/D layout col=lane&31 (=s), row=(r&3)+8*(r>>2)+4*half (=o) ----
    float* op = out + ((size_t)b * COUT + wv * 32) * HW + s0;
    #pragma unroll
    for (int c = 0; c < 4; ++c) {
        int s = c * 32 + srow;
        #pragma unroll
        for (int r = 0; r < 16; ++r) {
            int row = (r & 3) + 8 * (r >> 2) + 4 * half;
            op[(size_t)row * HW + s] = acc[c][r];   // 128B segments per store instr
        }
    }
}

extern "C" void kernel_launch(void* const* d_in, const int* in_sizes, int n_in,
                              void* d_out, int out_size, void* d_ws, size_t ws_size,
                              hipStream_t stream) {
    const float* x = (const float*)d_in[0];
    const float* w = (const float*)d_in[1];
    float* out = (float*)d_out;
    unsigned short* wt = (unsigned short*)d_ws;   // 32 KB

    conv_prep<<<64, 256, 0, stream>>>(w, wt);
    conv_main<<<NB * (HW / 128), 256, 0, stream>>>(x, wt, out);
}

// Round 2
// 430.613 us; speedup vs baseline: 1.0090x; 1.0090x over previous
//
#include <hip/hip_runtime.h>

// 1x1 conv as batched GEMM: out[b] (COUT x HW) = Wt (COUT x CIN) * x[b] (CIN x HW)
// bf16 MFMA (fp32 accumulate). Memory-bound: 537MB total -> ~85us floor at 6.3TB/s.
// R2: float4 staging loads (16/thread vs 64 scalar), 3 blocks/CU, nontemporal streams.

#define HW   16384
#define CIN  128
#define COUT 128
#define NB   32

typedef __bf16 bf16x8 __attribute__((ext_vector_type(8)));
typedef float f32x16 __attribute__((ext_vector_type(16)));
typedef float f32x4 __attribute__((ext_vector_type(4)));
typedef unsigned short ushort8 __attribute__((ext_vector_type(8)));

__device__ __forceinline__ unsigned short f32_to_bf16(float f) {
    unsigned int u = __float_as_uint(f);
    u += 0x7FFFu + ((u >> 16) & 1u);   // round-to-nearest-even
    return (unsigned short)(u >> 16);
}

// W (CIN x COUT fp32) -> Wt (COUT x CIN bf16), transposed+converted, in ws.
__global__ void conv_prep(const float* __restrict__ w, unsigned short* __restrict__ wt) {
    int t = blockIdx.x * 256 + threadIdx.x;   // 64 blocks * 256 = 16384
    int i = t >> 7;      // cin
    int o = t & 127;     // cout (contiguous across lanes -> coalesced read)
    wt[o * CIN + i] = f32_to_bf16(w[i * COUT + o]);
}

__global__ __launch_bounds__(256, 3) void conv_main(
        const float* __restrict__ x, const unsigned short* __restrict__ wt,
        float* __restrict__ out) {
    // xT[s][i] bf16: 128 rows x 16 chunks of 8 elems (16B), chunk XOR-swizzled by (s&15).
    __shared__ unsigned short lds[CIN * 128];   // 32 KB

    const int bx = blockIdx.x;
    const int b  = bx >> 7;             // batch
    const int s0 = (bx & 127) * 128;    // spatial tile start

    const int t    = threadIdx.x;
    const int lane = t & 63;
    const int wv   = t >> 6;            // wave 0..3

    // ---- A fragments from global Wt (32KB, L1/L2-hot) — issue first ----
    // A[m=o][k = kstep*16 + half*8 + j], j=0..7 contiguous
    bf16x8 afrag[8];
    {
        int o    = wv * 32 + (lane & 31);
        int half = lane >> 5;
        const char* wp = (const char*)wt + (size_t)(o * CIN + half * 8) * 2;
        #pragma unroll
        for (int k = 0; k < 8; ++k)
            afrag[k] = *(const bf16x8*)(wp + k * 32);   // 16B dwordx4
    }

    // ---- stage x tile (CIN x 128) -> LDS bf16 xT[s][i], swizzled ----
    // Thread t: s = 4*(t&31) .. +3 ; rows 8*(t>>5)+j+64*oct, j=0..7.
    // Each wave-instr load = 2 x 512B contiguous segments.
    {
        const int sl = (t & 31) * 4;
        const int rg = t >> 5;                       // row-group 0..7
        const float* xb = x + (size_t)b * CIN * HW + s0 + sl;
        #pragma unroll
        for (int oct = 0; oct < 2; ++oct) {
            const int ibase = rg * 8 + oct * 64;     // contiguous 8-row octet
            const int c8    = rg + oct * 8;          // i-chunk index = ibase>>3
            f32x4 v[8];
            #pragma unroll
            for (int j = 0; j < 8; ++j)
                v[j] = __builtin_nontemporal_load(
                        (const f32x4*)(xb + (size_t)(ibase + j) * HW));
            #pragma unroll
            for (int k = 0; k < 4; ++k) {            // 4 s values per thread
                int s = sl + k;
                ushort8 p;
                #pragma unroll
                for (int j = 0; j < 8; ++j)
                    p[j] = f32_to_bf16(v[j][k]);     // element j -> i = c8*8+j
                int chunk = c8 ^ (s & 15);
                *(ushort8*)((char*)lds + s * 256 + chunk * 16) = p;  // ds_write_b128
            }
        }
    }

    __syncthreads();

    // ---- K loop: wave computes o in [32*wv, 32*wv+32), all 128 s ----
    f32x16 acc[4];
    #pragma unroll
    for (int c = 0; c < 4; ++c) acc[c] = (f32x16)(0.0f);

    const int srow = lane & 31;
    const int half = lane >> 5;
    #pragma unroll
    for (int k = 0; k < 8; ++k) {
        int cbase = k * 2 + half;                  // i-chunk for this frag
        #pragma unroll
        for (int c = 0; c < 4; ++c) {
            int s = c * 32 + srow;
            int chunk = cbase ^ (s & 15);
            bf16x8 bfrag = *(const bf16x8*)((const char*)lds + s * 256 + chunk * 16);
            acc[c] = __builtin_amdgcn_mfma_f32_32x32x16_bf16(afrag[k], bfrag, acc[c], 0, 0, 0);
        }
    }

    // ---- epilogue: C/D layout col=lane&31 (=s), row=(r&3)+8*(r>>2)+4*half (=o) ----
    float* op = out + ((size_t)b * COUT + wv * 32) * HW + s0;
    #pragma unroll
    for (int c = 0; c < 4; ++c) {
        int s = c * 32 + srow;
        #pragma unroll
        for (int r = 0; r < 16; ++r) {
            int row = (r & 3) + 8 * (r >> 2) + 4 * half;
            __builtin_nontemporal_store(acc[c][r], op + (size_t)row * HW + s);
        }
    }
}

extern "C" void kernel_launch(void* const* d_in, const int* in_sizes, int n_in,
                              void* d_out, int out_size, void* d_ws, size_t ws_size,
                              hipStream_t stream) {
    const float* x = (const float*)d_in[0];
    const float* w = (const float*)d_in[1];
    float* out = (float*)d_out;
    unsigned short* wt = (unsigned short*)d_ws;   // 32 KB

    conv_prep<<<64, 256, 0, stream>>>(w, wt);
    conv_main<<<NB * (HW / 128), 256, 0, stream>>>(x, wt, out);
}